// Round 1
// baseline (851.959 us; speedup 1.0000x reference)
//
#include <hip/hip_runtime.h>
#include <hip/hip_bf16.h>

#define DEVI __device__ __forceinline__

typedef __attribute__((ext_vector_type(8))) __bf16 bf16x8;
typedef __attribute__((ext_vector_type(4))) float f32x4;

DEVI f32x4 mfma_16x16x32(bf16x8 a, bf16x8 b, f32x4 c) {
  return __builtin_amdgcn_mfma_f32_16x16x32_bf16(a, b, c, 0, 0, 0);
}

// async global->LDS, 16B per lane; LDS dest = wave-uniform base + lane*16
DEVI void gld16(const void* g, void* l) {
  __builtin_amdgcn_global_load_lds(
      reinterpret_cast<const __attribute__((address_space(1))) unsigned int*>(
          reinterpret_cast<unsigned long long>(g)),
      reinterpret_cast<__attribute__((address_space(3))) unsigned int*>(
          reinterpret_cast<unsigned long long>(l)),
      16, 0, 0);
}

DEVI unsigned short f2bf(float f) {
  unsigned u = __builtin_bit_cast(unsigned, f);
  u += 0x7FFFu + ((u >> 16) & 1u);   // RNE
  return (unsigned short)(u >> 16);
}
DEVI float bf2f(unsigned short b) {
  return __builtin_bit_cast(float, (unsigned)b << 16);
}

// ---------------- fp32 -> bf16 conversion ----------------
__global__ void k_conv(const float4* __restrict__ in, ushort4* __restrict__ out, int n4) {
  int stride = gridDim.x * blockDim.x;
  for (int i = blockIdx.x * blockDim.x + threadIdx.x; i < n4; i += stride) {
    float4 v = in[i];
    ushort4 o;
    o.x = f2bf(v.x); o.y = f2bf(v.y); o.z = f2bf(v.z); o.w = f2bf(v.w);
    out[i] = o;
  }
}

// ---------------- RoPE table: tab[s*64+d] = (cos, sin) of s * theta^(-d/64) ----------------
__global__ void k_rope_table(float2* __restrict__ tab) {
  int idx = blockIdx.x * blockDim.x + threadIdx.x;   // 2048*64
  int s = idx >> 6, d = idx & 63;
  float invf = powf(10000.0f, -(float)d * (1.0f / 64.0f));
  float f = (float)s * invf;
  tab[idx] = make_float2(cosf(f), sinf(f));
}

// ---------------- RoPE apply (in-place), optional scale folded in ----------------
template <int NH_>
__global__ void k_rope(unsigned short* __restrict__ X, const float2* __restrict__ tab,
                       const int* __restrict__ pos, float scale) {
  constexpr int PR = NH_ * 64;                 // pairs per row (power of 2)
  int idx = blockIdx.x * blockDim.x + threadIdx.x;   // 2048*PR total
  int s = idx / PR;
  int rem = idx - s * PR;
  int h = rem >> 6, d = rem & 63;
  size_t base = (size_t)s * (NH_ * 128) + h * 128 + d;
  float x1 = bf2f(X[base]);
  float x2 = bf2f(X[base + 64]);
  float2 cs = tab[(size_t)pos[s] * 64 + d];
  X[base]      = f2bf((x1 * cs.x - x2 * cs.y) * scale);
  X[base + 64] = f2bf((x2 * cs.x + x1 * cs.y) * scale);
}

// ---------------- GEMM: C = A(MxK) * B(NxK)^T, m97 structure ----------------
// MODE 0: bf16 C[row*N+col]; MODE 1: f32 C[row*N+col]; MODE 2: bf16 transposed C[col*M+row]
template <int MODE>
__global__ __launch_bounds__(256, 2)
void k_gemm_bt(const unsigned short* __restrict__ A,
               const unsigned short* __restrict__ B,
               void* __restrict__ Cp, int M, int N, int K) {
  constexpr int BK = 32;
  __shared__ __align__(16) unsigned short As[128][BK];
  __shared__ __align__(16) unsigned short Bs[128][BK];
  const int tid  = threadIdx.x;
  const int lane = tid & 63;
  const int wave = tid >> 6;
  const int bm = blockIdx.y * 128;
  const int bn = blockIdx.x * 128;
  const int wm = (wave >> 1) * 64;
  const int wn = (wave & 1) * 64;
  const int l15 = lane & 15;
  const int lg  = lane >> 4;

  f32x4 acc[4][4] = {};

  // staging: wave w owns rows [w*32, w*32+32) of each tile, 2 chunks of 16 rows
  const int srow = lane >> 2;          // 0..15
  const int scol = (lane & 3) * 8;     // element offset within row
  const unsigned short* aS0 = A + (size_t)(bm + wave * 32 + srow) * K + scol;
  const unsigned short* aS1 = aS0 + (size_t)16 * K;
  const unsigned short* bS0 = B + (size_t)(bn + wave * 32 + srow) * K + scol;
  const unsigned short* bS1 = bS0 + (size_t)16 * K;

  for (int k0 = 0; k0 < K; k0 += BK) {
    __syncthreads();                       // previous iter's LDS reads complete
    gld16(aS0 + k0, &As[wave * 32][0]);
    gld16(aS1 + k0, &As[wave * 32 + 16][0]);
    gld16(bS0 + k0, &Bs[wave * 32][0]);
    gld16(bS1 + k0, &Bs[wave * 32 + 16][0]);
    __syncthreads();                       // staged data visible (vmcnt drained)

    bf16x8 a[4], b[4];
#pragma unroll
    for (int m = 0; m < 4; ++m) a[m] = *(const bf16x8*)&As[wm + m * 16 + l15][lg * 8];
#pragma unroll
    for (int n = 0; n < 4; ++n) b[n] = *(const bf16x8*)&Bs[wn + n * 16 + l15][lg * 8];
#pragma unroll
    for (int m = 0; m < 4; ++m)
#pragma unroll
      for (int n = 0; n < 4; ++n)
        acc[m][n] = mfma_16x16x32(a[m], b[n], acc[m][n]);
  }

#pragma unroll
  for (int m = 0; m < 4; ++m)
#pragma unroll
    for (int n = 0; n < 4; ++n)
#pragma unroll
      for (int r = 0; r < 4; ++r) {
        int row = bm + wm + m * 16 + lg * 4 + r;
        int col = bn + wn + n * 16 + l15;
        float v = acc[m][n][r];
        if (MODE == 0)      ((unsigned short*)Cp)[(size_t)row * N + col] = f2bf(v);
        else if (MODE == 1) ((float*)Cp)[(size_t)row * N + col] = v;
        else                ((unsigned short*)Cp)[(size_t)col * M + row] = f2bf(v);
      }
}

// ---------------- Flash attention (causal, GQA 32Q/8KV, HD=128) ----------------
// grid: (32 q-superblocks of 64 rows, 32 heads); block: 4 waves, wave w owns rows q0+w*16..+15
__global__ __launch_bounds__(256, 2)
void k_attn(const unsigned short* __restrict__ Q,    // [2048][4096], pre-scaled by 1/sqrt(128)
            const unsigned short* __restrict__ Kb,   // [2048][1024]
            const unsigned short* __restrict__ Vt,   // [1024][2048]  (d-major)
            unsigned short* __restrict__ AO) {       // [2048][4096]
  __shared__ __align__(16) unsigned short Kl[32][128];
  __shared__ __align__(16) unsigned short Vl[128][32];
  __shared__ __align__(16) unsigned short Pl[4][16][40];   // padded rows (80B)
  const int tid = threadIdx.x, lane = tid & 63, w = tid >> 6;
  const int h  = blockIdx.y;
  const int q0 = blockIdx.x * 64;
  const int kh = h >> 2;                     // GQA: 4 q-heads per kv-head
  const int l15 = lane & 15, lg = lane >> 4;

  // Q fragments: A-layout row = l15, k = ks*32 + lg*8 .. +7
  bf16x8 qf[4];
  {
    const unsigned short* qr = Q + (size_t)(q0 + w * 16 + l15) * 4096 + h * 128;
#pragma unroll
    for (int ks = 0; ks < 4; ++ks) qf[ks] = *(const bf16x8*)(qr + ks * 32 + lg * 8);
  }

  f32x4 o[8] = {};
  float m_run[4], l_run[4];
#pragma unroll
  for (int r = 0; r < 4; ++r) { m_run[r] = -1e30f; l_run[r] = 0.f; }

  const int nkb   = q0 / 32 + 2;             // kv blocks of 32 covering rows <= q0+63
  const int qbase = q0 + w * 16 + lg * 4;    // this lane-group's first q row

  for (int kb = 0; kb < nkb; ++kb) {
    const int kv0 = kb * 32;
    __syncthreads();                         // protect K/V tiles from overwrite
    {                                        // wave w stages chunks 2w, 2w+1 of K and Vt
      const int c0 = 2 * w, c1 = 2 * w + 1;
      gld16(Kb + (size_t)(kv0 + 4 * c0 + lg) * 1024 + kh * 128 + l15 * 8, &Kl[4 * c0][0]);
      gld16(Kb + (size_t)(kv0 + 4 * c1 + lg) * 1024 + kh * 128 + l15 * 8, &Kl[4 * c1][0]);
      gld16(Vt + (size_t)(kh * 128 + 16 * c0 + (lane >> 2)) * 2048 + kv0 + (lane & 3) * 8, &Vl[16 * c0][0]);
      gld16(Vt + (size_t)(kh * 128 + 16 * c1 + (lane >> 2)) * 2048 + kv0 + (lane & 3) * 8, &Vl[16 * c1][0]);
    }
    __syncthreads();                         // staging complete

    // S = Q K^T  (16 q-rows x 32 kv-cols)
    f32x4 s0 = {0.f, 0.f, 0.f, 0.f}, s1 = {0.f, 0.f, 0.f, 0.f};
#pragma unroll
    for (int ks = 0; ks < 4; ++ks) {
      bf16x8 b0 = *(const bf16x8*)&Kl[l15][ks * 32 + lg * 8];
      bf16x8 b1 = *(const bf16x8*)&Kl[16 + l15][ks * 32 + lg * 8];
      s0 = mfma_16x16x32(qf[ks], b0, s0);
      s1 = mfma_16x16x32(qf[ks], b1, s1);
    }

    // causal mask + online softmax (D-layout: row = qbase+r, cols kv0+l15 / kv0+16+l15)
    float mx[4], p0[4], p1[4], fac[4], rs[4];
#pragma unroll
    for (int r = 0; r < 4; ++r) {
      float a0 = s0[r], a1 = s1[r];
      if (kv0 + l15 > qbase + r)      a0 = -1e30f;
      if (kv0 + 16 + l15 > qbase + r) a1 = -1e30f;
      s0[r] = a0; s1[r] = a1;
      mx[r] = fmaxf(a0, a1);
    }
#pragma unroll
    for (int off = 1; off < 16; off <<= 1)
#pragma unroll
      for (int r = 0; r < 4; ++r) mx[r] = fmaxf(mx[r], __shfl_xor(mx[r], off));
#pragma unroll
    for (int r = 0; r < 4; ++r) {
      float mn = fmaxf(m_run[r], mx[r]);
      fac[r] = __expf(m_run[r] - mn);
      m_run[r] = mn;
      p0[r] = __expf(s0[r] - mn);            // masked -> exp(-1e30 - mn) == 0
      p1[r] = __expf(s1[r] - mn);
      rs[r] = p0[r] + p1[r];
    }
#pragma unroll
    for (int off = 1; off < 16; off <<= 1)
#pragma unroll
      for (int r = 0; r < 4; ++r) rs[r] += __shfl_xor(rs[r], off);
#pragma unroll
    for (int r = 0; r < 4; ++r) l_run[r] = l_run[r] * fac[r] + rs[r];
#pragma unroll
    for (int j = 0; j < 8; ++j)
#pragma unroll
      for (int r = 0; r < 4; ++r) o[j][r] *= fac[r];

    // P (D-layout) -> LDS -> A-layout fragment
#pragma unroll
    for (int r = 0; r < 4; ++r) {
      Pl[w][lg * 4 + r][l15]      = f2bf(p0[r]);
      Pl[w][lg * 4 + r][16 + l15] = f2bf(p1[r]);
    }
    __syncthreads();                         // ordering safety (uniform across waves)
    bf16x8 pa = *(const bf16x8*)&Pl[w][l15][lg * 8];
#pragma unroll
    for (int j = 0; j < 8; ++j) {
      bf16x8 bv = *(const bf16x8*)&Vl[j * 16 + l15][lg * 8];
      o[j] = mfma_16x16x32(pa, bv, o[j]);
    }
  }

#pragma unroll
  for (int r = 0; r < 4; ++r) {
    float inv = 1.0f / l_run[r];
#pragma unroll
    for (int j = 0; j < 8; ++j)
      AO[(size_t)(qbase + r) * 4096 + h * 128 + j * 16 + l15] = f2bf(o[j][r] * inv);
  }
}

// ---------------- launch ----------------
extern "C" void kernel_launch(void* const* d_in, const int* in_sizes, int n_in,
                              void* d_out, int out_size, void* d_ws, size_t ws_size,
                              hipStream_t stream) {
  const float* x  = (const float*)d_in[0];
  const float* Wq = (const float*)d_in[1];
  const float* Wk = (const float*)d_in[2];
  const float* Wv = (const float*)d_in[3];
  const float* Wo = (const float*)d_in[4];
  const int*   pos = (const int*)d_in[5];
  float* out = (float*)d_out;

  char* p = (char*)d_ws;
  unsigned short* xb  = (unsigned short*)p; p += (size_t)2048 * 4096 * 2;
  unsigned short* wqb = (unsigned short*)p; p += (size_t)4096 * 4096 * 2;
  unsigned short* wkb = (unsigned short*)p; p += (size_t)1024 * 4096 * 2;
  unsigned short* wvb = (unsigned short*)p; p += (size_t)1024 * 4096 * 2;
  unsigned short* wob = (unsigned short*)p; p += (size_t)4096 * 4096 * 2;
  unsigned short* qb  = (unsigned short*)p; p += (size_t)2048 * 4096 * 2;
  unsigned short* kb  = (unsigned short*)p; p += (size_t)2048 * 1024 * 2;
  unsigned short* vtb = (unsigned short*)p; p += (size_t)1024 * 2048 * 2;
  unsigned short* aob = (unsigned short*)p; p += (size_t)2048 * 4096 * 2;
  float2*         tab = (float2*)p;         p += (size_t)2048 * 64 * 8;

  k_conv<<<2048, 256, 0, stream>>>((const float4*)x,  (ushort4*)xb,  2048 * 4096 / 4);
  k_conv<<<2048, 256, 0, stream>>>((const float4*)Wq, (ushort4*)wqb, 4096 * 4096 / 4);
  k_conv<<<1024, 256, 0, stream>>>((const float4*)Wk, (ushort4*)wkb, 1024 * 4096 / 4);
  k_conv<<<1024, 256, 0, stream>>>((const float4*)Wv, (ushort4*)wvb, 1024 * 4096 / 4);
  k_conv<<<2048, 256, 0, stream>>>((const float4*)Wo, (ushort4*)wob, 4096 * 4096 / 4);
  k_rope_table<<<512, 256, 0, stream>>>(tab);

  k_gemm_bt<0><<<dim3(32, 16), 256, 0, stream>>>(xb, wqb, qb,  2048, 4096, 4096);
  k_gemm_bt<0><<<dim3(8, 16),  256, 0, stream>>>(xb, wkb, kb,  2048, 1024, 4096);
  k_gemm_bt<2><<<dim3(8, 16),  256, 0, stream>>>(xb, wvb, vtb, 2048, 1024, 4096);

  const float scale = 0.08838834764831845f;  // 1/sqrt(128), folded into Q
  k_rope<32><<<2048 * 2048 / 256, 256, 0, stream>>>(qb, tab, pos, scale);
  k_rope<8><<<2048 * 512 / 256,  256, 0, stream>>>(kb, tab, pos, 1.0f);

  k_attn<<<dim3(32, 32), 256, 0, stream>>>(qb, kb, vtb, aob);

  k_gemm_bt<1><<<dim3(32, 16), 256, 0, stream>>>(aob, wob, out, 2048, 4096, 4096);
}

// Round 2
// 738.668 us; speedup vs baseline: 1.1534x; 1.1534x over previous
//
#include <hip/hip_runtime.h>
#include <hip/hip_bf16.h>

#define DEVI __device__ __forceinline__

typedef __attribute__((ext_vector_type(8))) __bf16 bf16x8;
typedef __attribute__((ext_vector_type(4))) float f32x4;

DEVI f32x4 mfma_16x16x32(bf16x8 a, bf16x8 b, f32x4 c) {
  return __builtin_amdgcn_mfma_f32_16x16x32_bf16(a, b, c, 0, 0, 0);
}

// async global->LDS, 16B per lane; LDS dest = wave-uniform base + lane*16
DEVI void gld16(const void* g, void* l) {
  __builtin_amdgcn_global_load_lds(
      reinterpret_cast<const __attribute__((address_space(1))) unsigned int*>(
          reinterpret_cast<unsigned long long>(g)),
      reinterpret_cast<__attribute__((address_space(3))) unsigned int*>(
          reinterpret_cast<unsigned long long>(l)),
      16, 0, 0);
}

DEVI unsigned short f2bf(float f) {
  unsigned u = __builtin_bit_cast(unsigned, f);
  u += 0x7FFFu + ((u >> 16) & 1u);   // RNE
  return (unsigned short)(u >> 16);
}
DEVI float bf2f(unsigned short b) {
  return __builtin_bit_cast(float, (unsigned)b << 16);
}

// ---------------- fp32 -> bf16 conversion ----------------
__global__ void k_conv(const float4* __restrict__ in, ushort4* __restrict__ out, int n4) {
  int stride = gridDim.x * blockDim.x;
  for (int i = blockIdx.x * blockDim.x + threadIdx.x; i < n4; i += stride) {
    float4 v = in[i];
    ushort4 o;
    o.x = f2bf(v.x); o.y = f2bf(v.y); o.z = f2bf(v.z); o.w = f2bf(v.w);
    out[i] = o;
  }
}

// ---------------- RoPE table: tab[s*64+d] = (cos, sin) of s * theta^(-d/64) ----------------
__global__ void k_rope_table(float2* __restrict__ tab) {
  int idx = blockIdx.x * blockDim.x + threadIdx.x;   // 2048*64
  int s = idx >> 6, d = idx & 63;
  float invf = powf(10000.0f, -(float)d * (1.0f / 64.0f));
  float f = (float)s * invf;
  tab[idx] = make_float2(cosf(f), sinf(f));
}

// ---------------- RoPE apply (in-place), optional scale folded in ----------------
template <int NH_>
__global__ void k_rope(unsigned short* __restrict__ X, const float2* __restrict__ tab,
                       const int* __restrict__ pos, float scale) {
  constexpr int PR = NH_ * 64;                 // pairs per row (power of 2)
  int idx = blockIdx.x * blockDim.x + threadIdx.x;   // 2048*PR total
  int s = idx / PR;
  int rem = idx - s * PR;
  int h = rem >> 6, d = rem & 63;
  size_t base = (size_t)s * (NH_ * 128) + h * 128 + d;
  float x1 = bf2f(X[base]);
  float x2 = bf2f(X[base + 64]);
  float2 cs = tab[(size_t)pos[s] * 64 + d];
  X[base]      = f2bf((x1 * cs.x - x2 * cs.y) * scale);
  X[base + 64] = f2bf((x2 * cs.x + x1 * cs.y) * scale);
}

// ---------------- GEMM: C = A(MxK) * B(NxK)^T, m97 structure ----------------
// MODE 0: bf16 C[row*N+col]; MODE 1: f32 C[row*N+col]; MODE 2: bf16 transposed C[col*M+row]
template <int MODE>
__global__ __launch_bounds__(256, 2)
void k_gemm_bt(const unsigned short* __restrict__ A,
               const unsigned short* __restrict__ B,
               void* __restrict__ Cp, int M, int N, int K) {
  constexpr int BK = 32;
  __shared__ __align__(16) unsigned short As[128][BK];
  __shared__ __align__(16) unsigned short Bs[128][BK];
  const int tid  = threadIdx.x;
  const int lane = tid & 63;
  const int wave = tid >> 6;
  const int bm = blockIdx.y * 128;
  const int bn = blockIdx.x * 128;
  const int wm = (wave >> 1) * 64;
  const int wn = (wave & 1) * 64;
  const int l15 = lane & 15;
  const int lg  = lane >> 4;

  f32x4 acc[4][4] = {};

  const int srow = lane >> 2;          // 0..15
  const int scol = (lane & 3) * 8;     // element offset within row
  const unsigned short* aS0 = A + (size_t)(bm + wave * 32 + srow) * K + scol;
  const unsigned short* aS1 = aS0 + (size_t)16 * K;
  const unsigned short* bS0 = B + (size_t)(bn + wave * 32 + srow) * K + scol;
  const unsigned short* bS1 = bS0 + (size_t)16 * K;

  for (int k0 = 0; k0 < K; k0 += BK) {
    __syncthreads();
    gld16(aS0 + k0, &As[wave * 32][0]);
    gld16(aS1 + k0, &As[wave * 32 + 16][0]);
    gld16(bS0 + k0, &Bs[wave * 32][0]);
    gld16(bS1 + k0, &Bs[wave * 32 + 16][0]);
    __syncthreads();

    bf16x8 a[4], b[4];
#pragma unroll
    for (int m = 0; m < 4; ++m) a[m] = *(const bf16x8*)&As[wm + m * 16 + l15][lg * 8];
#pragma unroll
    for (int n = 0; n < 4; ++n) b[n] = *(const bf16x8*)&Bs[wn + n * 16 + l15][lg * 8];
#pragma unroll
    for (int m = 0; m < 4; ++m)
#pragma unroll
      for (int n = 0; n < 4; ++n)
        acc[m][n] = mfma_16x16x32(a[m], b[n], acc[m][n]);
  }

#pragma unroll
  for (int m = 0; m < 4; ++m)
#pragma unroll
    for (int n = 0; n < 4; ++n)
#pragma unroll
      for (int r = 0; r < 4; ++r) {
        int row = bm + wm + m * 16 + lg * 4 + r;
        int col = bn + wn + n * 16 + l15;
        float v = acc[m][n][r];
        if (MODE == 0)      ((unsigned short*)Cp)[(size_t)row * N + col] = f2bf(v);
        else if (MODE == 1) ((float*)Cp)[(size_t)row * N + col] = v;
        else                ((unsigned short*)Cp)[(size_t)col * M + row] = f2bf(v);
      }
}

// ---------------- Flash attention v2 ----------------
// causal, GQA 32Q/8KV, HD=128. KVBLK=64, double-buffered K/V, XOR-swizzled LDS.
// LDS-swizzle invariant: row r, 16B-chunk-slot c holds data chunk c ^ (r&7).
// grid: (32 q-blocks [reversed for load balance], 32 heads); 4 waves; wave w owns 16 q-rows.
__global__ __launch_bounds__(256, 2)
void k_attn(const unsigned short* __restrict__ Q,    // [2048][4096], pre-scaled by 1/sqrt(128)
            const unsigned short* __restrict__ Kb,   // [2048][1024]
            const unsigned short* __restrict__ Vt,   // [1024][2048]  (d-major)
            unsigned short* __restrict__ AO) {       // [2048][4096]
  __shared__ __align__(16) unsigned short Kl[2][64][128];  // 32 KB
  __shared__ __align__(16) unsigned short Vl[2][128][64];  // 32 KB
  __shared__ __align__(16) unsigned short Pl[4][16][72];   // 9 KB (padded rows)
  const int tid = threadIdx.x, lane = tid & 63, w = tid >> 6;
  const int h  = blockIdx.y;
  const int qi = (int)gridDim.x - 1 - (int)blockIdx.x;   // reversed: heavy blocks first
  const int q0 = qi * 64;
  const int kh = h >> 2;                     // GQA: 4 q-heads per kv-head
  const int l15 = lane & 15, lg = lane >> 4;

  // Q fragments: A-layout row = l15, k = ks*32 + lg*8 .. +7
  bf16x8 qf[4];
  {
    const unsigned short* qr = Q + (size_t)(q0 + w * 16 + l15) * 4096 + h * 128;
#pragma unroll
    for (int ks = 0; ks < 4; ++ks) qf[ks] = *(const bf16x8*)(qr + ks * 32 + lg * 8);
  }

  f32x4 o[8] = {};
  float m_run[4], l_run[4];
#pragma unroll
  for (int r = 0; r < 4; ++r) { m_run[r] = -1e30f; l_run[r] = 0.f; }

  const int nkb   = qi + 1;                  // kv tiles of 64 covering rows <= q0+63
  const int qbase = q0 + w * 16 + lg * 4;

  // ---- staging (pre-swizzled global source, linear LDS dest) ----
  auto stageK = [&](int buf, int kv0) {      // wave w: rows 16w..16w+15
#pragma unroll
    for (int c = 0; c < 4; ++c) {
      int row = 16 * w + 4 * c + lg;         // this lane's dest row; chunk = l15
      gld16(Kb + (size_t)(kv0 + row) * 1024 + kh * 128 + ((l15 ^ (row & 7)) * 8),
            &Kl[buf][16 * w + 4 * c][0]);
    }
  };
  auto stageV = [&](int buf, int kv0) {      // wave w: rows 32w..32w+31 (d-major)
#pragma unroll
    for (int c = 0; c < 4; ++c) {
      int row = 32 * w + 8 * c + (lane >> 3); // this lane's dest row; chunk = lane&7
      gld16(Vt + (size_t)(kh * 128 + row) * 2048 + kv0 + (((lane & 7) ^ (row & 7)) * 8),
            &Vl[buf][32 * w + 8 * c][0]);
    }
  };

  stageK(0, 0);
  stageV(0, 0);
  int cur = 0;

  for (int kb = 0; kb < nkb; ++kb) {
    const int kv0 = kb * 64;
    __syncthreads();   // drains vmcnt: buf[cur] ready; all waves done reading buf[cur^1]
    if (kb + 1 < nkb) { stageK(cur ^ 1, kv0 + 64); stageV(cur ^ 1, kv0 + 64); }

    // S = Q K^T  (16 q-rows x 64 kv-cols), swizzled K reads
    f32x4 s[4] = {};
#pragma unroll
    for (int ks = 0; ks < 4; ++ks) {
#pragma unroll
      for (int n = 0; n < 4; ++n) {
        bf16x8 bk = *(const bf16x8*)&Kl[cur][n * 16 + l15][((ks * 4 + lg) ^ (l15 & 7)) * 8];
        s[n] = mfma_16x16x32(qf[ks], bk, s[n]);
      }
    }

    // causal mask (diagonal tile only) + online softmax
    if (kb == nkb - 1) {
#pragma unroll
      for (int n = 0; n < 4; ++n)
#pragma unroll
        for (int r = 0; r < 4; ++r)
          if (kv0 + n * 16 + l15 > qbase + r) s[n][r] = -1e30f;
    }
    float mx[4], fac[4], rs[4];
#pragma unroll
    for (int r = 0; r < 4; ++r)
      mx[r] = fmaxf(fmaxf(s[0][r], s[1][r]), fmaxf(s[2][r], s[3][r]));
#pragma unroll
    for (int off = 1; off < 16; off <<= 1)
#pragma unroll
      for (int r = 0; r < 4; ++r) mx[r] = fmaxf(mx[r], __shfl_xor(mx[r], off));
#pragma unroll
    for (int r = 0; r < 4; ++r) {
      float mn = fmaxf(m_run[r], mx[r]);
      fac[r] = __expf(m_run[r] - mn);
      m_run[r] = mn;
      rs[r] = 0.f;
#pragma unroll
      for (int n = 0; n < 4; ++n) {
        float p = __expf(s[n][r] - mn);
        s[n][r] = p;
        rs[r] += p;
      }
    }
#pragma unroll
    for (int off = 1; off < 16; off <<= 1)
#pragma unroll
      for (int r = 0; r < 4; ++r) rs[r] += __shfl_xor(rs[r], off);
#pragma unroll
    for (int r = 0; r < 4; ++r) l_run[r] = l_run[r] * fac[r] + rs[r];
#pragma unroll
    for (int j = 0; j < 8; ++j)
#pragma unroll
      for (int r = 0; r < 4; ++r) o[j][r] *= fac[r];

    // P (D-layout) -> per-wave LDS -> A-layout fragments (no barrier: wave-local)
#pragma unroll
    for (int n = 0; n < 4; ++n)
#pragma unroll
      for (int r = 0; r < 4; ++r)
        Pl[w][lg * 4 + r][n * 16 + l15] = f2bf(s[n][r]);
    asm volatile("s_waitcnt lgkmcnt(0)" ::: "memory");
    bf16x8 pa0 = *(const bf16x8*)&Pl[w][l15][lg * 8];
    bf16x8 pa1 = *(const bf16x8*)&Pl[w][l15][32 + lg * 8];

    // O += P V  (swizzled V reads; B-frag row = d, k = kv)
#pragma unroll
    for (int j = 0; j < 8; ++j) {
      bf16x8 bv0 = *(const bf16x8*)&Vl[cur][j * 16 + l15][(lg ^ (l15 & 7)) * 8];
      bf16x8 bv1 = *(const bf16x8*)&Vl[cur][j * 16 + l15][((4 + lg) ^ (l15 & 7)) * 8];
      o[j] = mfma_16x16x32(pa0, bv0, o[j]);
      o[j] = mfma_16x16x32(pa1, bv1, o[j]);
    }
    cur ^= 1;
  }

#pragma unroll
  for (int r = 0; r < 4; ++r) {
    float inv = 1.0f / l_run[r];
#pragma unroll
    for (int j = 0; j < 8; ++j)
      AO[(size_t)(qbase + r) * 4096 + h * 128 + j * 16 + l15] = f2bf(o[j][r] * inv);
  }
}

// ---------------- launch ----------------
extern "C" void kernel_launch(void* const* d_in, const int* in_sizes, int n_in,
                              void* d_out, int out_size, void* d_ws, size_t ws_size,
                              hipStream_t stream) {
  const float* x  = (const float*)d_in[0];
  const float* Wq = (const float*)d_in[1];
  const float* Wk = (const float*)d_in[2];
  const float* Wv = (const float*)d_in[3];
  const float* Wo = (const float*)d_in[4];
  const int*   pos = (const int*)d_in[5];
  float* out = (float*)d_out;

  char* p = (char*)d_ws;
  unsigned short* xb  = (unsigned short*)p; p += (size_t)2048 * 4096 * 2;
  unsigned short* wqb = (unsigned short*)p; p += (size_t)4096 * 4096 * 2;
  unsigned short* wkb = (unsigned short*)p; p += (size_t)1024 * 4096 * 2;
  unsigned short* wvb = (unsigned short*)p; p += (size_t)1024 * 4096 * 2;
  unsigned short* wob = (unsigned short*)p; p += (size_t)4096 * 4096 * 2;
  unsigned short* qb  = (unsigned short*)p; p += (size_t)2048 * 4096 * 2;
  unsigned short* kb  = (unsigned short*)p; p += (size_t)2048 * 1024 * 2;
  unsigned short* vtb = (unsigned short*)p; p += (size_t)1024 * 2048 * 2;
  unsigned short* aob = (unsigned short*)p; p += (size_t)2048 * 4096 * 2;
  float2*         tab = (float2*)p;         p += (size_t)2048 * 64 * 8;

  k_conv<<<2048, 256, 0, stream>>>((const float4*)x,  (ushort4*)xb,  2048 * 4096 / 4);
  k_conv<<<2048, 256, 0, stream>>>((const float4*)Wq, (ushort4*)wqb, 4096 * 4096 / 4);
  k_conv<<<1024, 256, 0, stream>>>((const float4*)Wk, (ushort4*)wkb, 1024 * 4096 / 4);
  k_conv<<<1024, 256, 0, stream>>>((const float4*)Wv, (ushort4*)wvb, 1024 * 4096 / 4);
  k_conv<<<2048, 256, 0, stream>>>((const float4*)Wo, (ushort4*)wob, 4096 * 4096 / 4);
  k_rope_table<<<512, 256, 0, stream>>>(tab);

  k_gemm_bt<0><<<dim3(32, 16), 256, 0, stream>>>(xb, wqb, qb,  2048, 4096, 4096);
  k_gemm_bt<0><<<dim3(8, 16),  256, 0, stream>>>(xb, wkb, kb,  2048, 1024, 4096);
  k_gemm_bt<2><<<dim3(8, 16),  256, 0, stream>>>(xb, wvb, vtb, 2048, 1024, 4096);

  const float scale = 0.08838834764831845f;  // 1/sqrt(128), folded into Q
  k_rope<32><<<2048 * 2048 / 256, 256, 0, stream>>>(qb, tab, pos, scale);
  k_rope<8><<<2048 * 512 / 256,  256, 0, stream>>>(kb, tab, pos, 1.0f);

  k_attn<<<dim3(32, 32), 256, 0, stream>>>(qb, kb, vtb, aob);

  k_gemm_bt<1><<<dim3(32, 16), 256, 0, stream>>>(aob, wob, out, 2048, 4096, 4096);
}

// Round 3
// 560.058 us; speedup vs baseline: 1.5212x; 1.3189x over previous
//
#include <hip/hip_runtime.h>
#include <hip/hip_bf16.h>

#define DEVI __device__ __forceinline__

typedef __attribute__((ext_vector_type(8))) __bf16 bf16x8;
typedef __attribute__((ext_vector_type(4))) float f32x4;

DEVI f32x4 mfma_16x16x32(bf16x8 a, bf16x8 b, f32x4 c) {
  return __builtin_amdgcn_mfma_f32_16x16x32_bf16(a, b, c, 0, 0, 0);
}

// async global->LDS, 16B per lane; LDS dest = wave-uniform base + lane*16
DEVI void gld16(const void* g, void* l) {
  __builtin_amdgcn_global_load_lds(
      reinterpret_cast<const __attribute__((address_space(1))) unsigned int*>(
          reinterpret_cast<unsigned long long>(g)),
      reinterpret_cast<__attribute__((address_space(3))) unsigned int*>(
          reinterpret_cast<unsigned long long>(l)),
      16, 0, 0);
}

DEVI unsigned short f2bf(float f) {
  unsigned u = __builtin_bit_cast(unsigned, f);
  u += 0x7FFFu + ((u >> 16) & 1u);   // RNE
  return (unsigned short)(u >> 16);
}
DEVI float bf2f(unsigned short b) {
  return __builtin_bit_cast(float, (unsigned)b << 16);
}

// ---------------- fused fp32 -> bf16 conversion (all 5 tensors, 1 launch) ----------------
struct Conv5 {
  const float4 *x, *wq, *wk, *wv, *wo;
  ushort4 *xb, *wqb, *wkv, *wob;
};
__global__ void k_conv_all(Conv5 a) {
  constexpr int C0 = 2097152;            // x      2048*4096/4
  constexpr int C1 = C0 + 4194304;       // Wq     4096*4096/4
  constexpr int C2 = C1 + 1048576;       // Wk     1024*4096/4
  constexpr int C3 = C2 + 1048576;       // Wv
  constexpr int C4 = C3 + 4194304;       // Wo
  int stride = gridDim.x * blockDim.x;
  for (int i = blockIdx.x * blockDim.x + threadIdx.x; i < C4; i += stride) {
    const float4* src; ushort4* dst; int j;
    if (i < C0)      { src = a.x;  dst = a.xb;            j = i; }
    else if (i < C1) { src = a.wq; dst = a.wqb;           j = i - C0; }
    else if (i < C2) { src = a.wk; dst = a.wkv;           j = i - C1; }
    else if (i < C3) { src = a.wv; dst = a.wkv + 1048576; j = i - C2; }
    else             { src = a.wo; dst = a.wob;           j = i - C3; }
    float4 v = src[j];
    ushort4 o; o.x = f2bf(v.x); o.y = f2bf(v.y); o.z = f2bf(v.z); o.w = f2bf(v.w);
    dst[j] = o;
  }
}

// ---------------- RoPE table: tab[s*64+d] = (cos, sin) of s * theta^(-d/64) ----------------
__global__ void k_rope_table(float2* __restrict__ tab) {
  int idx = blockIdx.x * blockDim.x + threadIdx.x;   // 2048*64
  int s = idx >> 6, d = idx & 63;
  float invf = powf(10000.0f, -(float)d * (1.0f / 64.0f));
  float f = (float)s * invf;
  tab[idx] = make_float2(cosf(f), sinf(f));
}

// ---------------- RoPE apply, vectorized: 8 (d,d+64) pairs per thread ----------------
template <int NH_, int L2NH>
__global__ void k_rope_v(unsigned short* __restrict__ X, const float2* __restrict__ tab,
                         const int* __restrict__ pos, float scale) {
  int t = blockIdx.x * blockDim.x + threadIdx.x;     // 2048*NH_*8 threads
  int d0 = (t & 7) * 8;
  int sh = t >> 3;
  int s  = sh >> L2NH;
  int h  = sh & (NH_ - 1);
  size_t base = (size_t)s * (NH_ * 128) + h * 128 + d0;
  const float4* tf = (const float4*)(tab + (size_t)pos[s] * 64 + d0);
  unsigned short a[8], b[8], oa[8], ob[8];
  *(ushort4*)&a[0] = *(const ushort4*)(X + base);
  *(ushort4*)&a[4] = *(const ushort4*)(X + base + 4);
  *(ushort4*)&b[0] = *(const ushort4*)(X + base + 64);
  *(ushort4*)&b[4] = *(const ushort4*)(X + base + 68);
#pragma unroll
  for (int j = 0; j < 4; ++j) {
    float4 cs = tf[j];                               // c(2j), s(2j), c(2j+1), s(2j+1)
    float x1 = bf2f(a[2*j]),   x2 = bf2f(b[2*j]);
    float y1 = bf2f(a[2*j+1]), y2 = bf2f(b[2*j+1]);
    oa[2*j]   = f2bf((x1 * cs.x - x2 * cs.y) * scale);
    ob[2*j]   = f2bf((x2 * cs.x + x1 * cs.y) * scale);
    oa[2*j+1] = f2bf((y1 * cs.z - y2 * cs.w) * scale);
    ob[2*j+1] = f2bf((y2 * cs.z + y1 * cs.w) * scale);
  }
  *(ushort4*)(X + base)      = *(ushort4*)&oa[0];
  *(ushort4*)(X + base + 4)  = *(ushort4*)&oa[4];
  *(ushort4*)(X + base + 64) = *(ushort4*)&ob[0];
  *(ushort4*)(X + base + 68) = *(ushort4*)&ob[4];
}

// ---------------- GEMM: C = A(MxK) * B(NxK)^T, m97 structure, 128x128 tile ----------------
// MODE 0: bf16 C[row*N+col]; MODE 1: f32 C[row*N+col]
template <int MODE>
__global__ __launch_bounds__(256, 2)
void k_gemm_bt(const unsigned short* __restrict__ A,
               const unsigned short* __restrict__ B,
               void* __restrict__ Cp, int M, int N, int K) {
  constexpr int BK = 32;
  __shared__ __align__(16) unsigned short As[128][BK];
  __shared__ __align__(16) unsigned short Bs[128][BK];
  const int tid  = threadIdx.x;
  const int lane = tid & 63;
  const int wave = tid >> 6;
  const int bm = blockIdx.y * 128;
  const int bn = blockIdx.x * 128;
  const int wm = (wave >> 1) * 64;
  const int wn = (wave & 1) * 64;
  const int l15 = lane & 15;
  const int lg  = lane >> 4;

  f32x4 acc[4][4] = {};

  const int srow = lane >> 2;
  const int scol = (lane & 3) * 8;
  const unsigned short* aS0 = A + (size_t)(bm + wave * 32 + srow) * K + scol;
  const unsigned short* aS1 = aS0 + (size_t)16 * K;
  const unsigned short* bS0 = B + (size_t)(bn + wave * 32 + srow) * K + scol;
  const unsigned short* bS1 = bS0 + (size_t)16 * K;

  for (int k0 = 0; k0 < K; k0 += BK) {
    __syncthreads();
    gld16(aS0 + k0, &As[wave * 32][0]);
    gld16(aS1 + k0, &As[wave * 32 + 16][0]);
    gld16(bS0 + k0, &Bs[wave * 32][0]);
    gld16(bS1 + k0, &Bs[wave * 32 + 16][0]);
    __syncthreads();

    bf16x8 a[4], b[4];
#pragma unroll
    for (int m = 0; m < 4; ++m) a[m] = *(const bf16x8*)&As[wm + m * 16 + l15][lg * 8];
#pragma unroll
    for (int n = 0; n < 4; ++n) b[n] = *(const bf16x8*)&Bs[wn + n * 16 + l15][lg * 8];
#pragma unroll
    for (int m = 0; m < 4; ++m)
#pragma unroll
      for (int n = 0; n < 4; ++n)
        acc[m][n] = mfma_16x16x32(a[m], b[n], acc[m][n]);
  }

#pragma unroll
  for (int m = 0; m < 4; ++m)
#pragma unroll
    for (int n = 0; n < 4; ++n)
#pragma unroll
      for (int r = 0; r < 4; ++r) {
        int row = bm + wm + m * 16 + lg * 4 + r;
        int col = bn + wn + n * 16 + l15;
        float v = acc[m][n][r];
        if (MODE == 0) ((unsigned short*)Cp)[(size_t)row * N + col] = f2bf(v);
        else           ((float*)Cp)[(size_t)row * N + col] = v;
      }
}

// ---------------- KV GEMM: BM=64 tile -> 512 blocks; split K / V^T epilogue ----------------
__global__ __launch_bounds__(256, 2)
void k_gemm_kv(const unsigned short* __restrict__ A,    // xb [2048][4096]
               const unsigned short* __restrict__ B,    // wkv [2048][4096]
               unsigned short* __restrict__ Kp,         // [2048][1024]
               unsigned short* __restrict__ Vtp,        // [1024][2048]
               int M, int K) {
  constexpr int BK = 32;
  __shared__ __align__(16) unsigned short As[64][BK];
  __shared__ __align__(16) unsigned short Bs[128][BK];
  const int tid = threadIdx.x, lane = tid & 63, wave = tid >> 6;
  const int bm = blockIdx.y * 64;
  const int bn = blockIdx.x * 128;
  const int wn = wave * 32;
  const int l15 = lane & 15, lg = lane >> 4;
  f32x4 acc[4][2] = {};
  const int srow = lane >> 2, scol = (lane & 3) * 8;
  const unsigned short* aS0 = A + (size_t)(bm + wave * 16 + srow) * K + scol;
  const unsigned short* bS0 = B + (size_t)(bn + wave * 32 + srow) * K + scol;
  const unsigned short* bS1 = bS0 + (size_t)16 * K;

  for (int k0 = 0; k0 < K; k0 += BK) {
    __syncthreads();
    gld16(aS0 + k0, &As[wave * 16][0]);
    gld16(bS0 + k0, &Bs[wave * 32][0]);
    gld16(bS1 + k0, &Bs[wave * 32 + 16][0]);
    __syncthreads();
    bf16x8 a[4], b[2];
#pragma unroll
    for (int m = 0; m < 4; ++m) a[m] = *(const bf16x8*)&As[m * 16 + l15][lg * 8];
#pragma unroll
    for (int n = 0; n < 2; ++n) b[n] = *(const bf16x8*)&Bs[wn + n * 16 + l15][lg * 8];
#pragma unroll
    for (int m = 0; m < 4; ++m)
#pragma unroll
      for (int n = 0; n < 2; ++n)
        acc[m][n] = mfma_16x16x32(a[m], b[n], acc[m][n]);
  }

#pragma unroll
  for (int m = 0; m < 4; ++m)
#pragma unroll
    for (int n = 0; n < 2; ++n)
#pragma unroll
      for (int r = 0; r < 4; ++r) {
        int row = bm + m * 16 + lg * 4 + r;
        int col = bn + wn + n * 16 + l15;
        float v = acc[m][n][r];
        if (col < 1024) Kp[(size_t)row * 1024 + col] = f2bf(v);
        else            Vtp[(size_t)(col - 1024) * 2048 + row] = f2bf(v);
      }
}

// ---------------- Flash attention v3: swapped QK^T, per-lane softmax ----------------
// causal, GQA 32Q/8KV, HD=128, KVBLK=64, double-buffered, XOR-swizzled LDS.
// S^T = mfma(K,Q): lane (lg,l15) holds S^T[kv0+n*16+lg*4+r][q=l15] -> softmax per-lane.
// O^T = mfma(Vt,P): lane holds O^T[d=j*16+lg*4+r][q=l15]; transposed out via LDS.
// grid: 1024 blocks 1-D, heavy q-blocks first; 4 waves, wave w owns q rows w*16..+15.
__global__ __launch_bounds__(256, 2)
void k_attn(const unsigned short* __restrict__ Q,    // [2048][4096], pre-scaled
            const unsigned short* __restrict__ Kb,   // [2048][1024]
            const unsigned short* __restrict__ Vt,   // [1024][2048]  (d-major)
            unsigned short* __restrict__ AO) {       // [2048][4096]
  __shared__ __align__(16) unsigned short Kl[2][64][128];  // 32 KB (reused as Ol[4][16][136])
  __shared__ __align__(16) unsigned short Vl[2][128][64];  // 32 KB
  __shared__ __align__(16) unsigned short Pl[4][16][72];   // 9 KB
  const int tid = threadIdx.x, lane = tid & 63, w = tid >> 6;
  const int bid = blockIdx.x;
  const int qi = 31 - (bid >> 5);            // heavy blocks dispatched first
  const int h  = bid & 31;
  const int q0 = qi * 64;
  const int kh = h >> 2;
  const int l15 = lane & 15, lg = lane >> 4;

  bf16x8 qf[4];
  {
    const unsigned short* qr = Q + (size_t)(q0 + w * 16 + l15) * 4096 + h * 128;
#pragma unroll
    for (int ks = 0; ks < 4; ++ks) qf[ks] = *(const bf16x8*)(qr + ks * 32 + lg * 8);
  }

  f32x4 o[8] = {};
  float m_run = -1e30f, l_run = 0.f;
  const int nkb = qi + 1;
  const int myq = q0 + w * 16 + l15;         // this lane's q row

  auto stageK = [&](int buf, int kv0) {
#pragma unroll
    for (int c = 0; c < 4; ++c) {
      int row = 16 * w + 4 * c + lg;
      gld16(Kb + (size_t)(kv0 + row) * 1024 + kh * 128 + ((l15 ^ (row & 7)) * 8),
            &Kl[buf][16 * w + 4 * c][0]);
    }
  };
  auto stageV = [&](int buf, int kv0) {
#pragma unroll
    for (int c = 0; c < 4; ++c) {
      int row = 32 * w + 8 * c + (lane >> 3);
      gld16(Vt + (size_t)(kh * 128 + row) * 2048 + kv0 + (((lane & 7) ^ (row & 7)) * 8),
            &Vl[buf][32 * w + 8 * c][0]);
    }
  };

  stageK(0, 0);
  stageV(0, 0);
  int cur = 0;

  for (int kb = 0; kb < nkb; ++kb) {
    const int kv0 = kb * 64;
    __syncthreads();                         // buf[cur] staged; buf[cur^1] free
    if (kb + 1 < nkb) { stageK(cur ^ 1, kv0 + 64); stageV(cur ^ 1, kv0 + 64); }

    // S^T = K Q^T  (64 kv-rows x 16 q-cols); q is lane-local (= l15)
    f32x4 s[4] = {};
    __builtin_amdgcn_s_setprio(1);
#pragma unroll
    for (int ks = 0; ks < 4; ++ks)
#pragma unroll
      for (int n = 0; n < 4; ++n) {
        bf16x8 bk = *(const bf16x8*)&Kl[cur][n * 16 + l15][((ks * 4 + lg) ^ (l15 & 7)) * 8];
        s[n] = mfma_16x16x32(bk, qf[ks], s[n]);
      }
    __builtin_amdgcn_s_setprio(0);

    if (kb == nkb - 1) {                     // causal mask: diagonal tile only
#pragma unroll
      for (int n = 0; n < 4; ++n)
#pragma unroll
        for (int r = 0; r < 4; ++r)
          if (kv0 + n * 16 + lg * 4 + r > myq) s[n][r] = -1e30f;
    }

    // per-lane softmax: 16 values of one q-row; cross-lane only over lg (xor 16,32)
    float mx = -1e30f;
#pragma unroll
    for (int n = 0; n < 4; ++n)
      mx = fmaxf(mx, fmaxf(fmaxf(s[n][0], s[n][1]), fmaxf(s[n][2], s[n][3])));
    mx = fmaxf(mx, __shfl_xor(mx, 16));
    mx = fmaxf(mx, __shfl_xor(mx, 32));
    float mn = fmaxf(m_run, mx);
    float fac = __expf(m_run - mn);
    m_run = mn;
    float rs = 0.f;
#pragma unroll
    for (int n = 0; n < 4; ++n)
#pragma unroll
      for (int r = 0; r < 4; ++r) {
        float pv = __expf(s[n][r] - mn);
        s[n][r] = pv;
        rs += pv;
      }
    rs += __shfl_xor(rs, 16);
    rs += __shfl_xor(rs, 32);
    l_run = l_run * fac + rs;
#pragma unroll
    for (int j = 0; j < 8; ++j) {
      o[j][0] *= fac; o[j][1] *= fac; o[j][2] *= fac; o[j][3] *= fac;
    }

    // P[q=l15][kv] -> per-wave LDS -> B-layout fragments (row=q, k=kv)
#pragma unroll
    for (int n = 0; n < 4; ++n)
#pragma unroll
      for (int r = 0; r < 4; ++r)
        Pl[w][l15][n * 16 + lg * 4 + r] = f2bf(s[n][r]);
    asm volatile("s_waitcnt lgkmcnt(0)" ::: "memory");
    bf16x8 pa0 = *(const bf16x8*)&Pl[w][l15][lg * 8];
    bf16x8 pa1 = *(const bf16x8*)&Pl[w][l15][32 + lg * 8];

    // O^T += V^T P^T  (A = Vt rows d, B = P rows q)
    __builtin_amdgcn_s_setprio(1);
#pragma unroll
    for (int j = 0; j < 8; ++j) {
      bf16x8 bv0 = *(const bf16x8*)&Vl[cur][j * 16 + l15][(lg ^ (l15 & 7)) * 8];
      bf16x8 bv1 = *(const bf16x8*)&Vl[cur][j * 16 + l15][((4 + lg) ^ (l15 & 7)) * 8];
      o[j] = mfma_16x16x32(bv0, pa0, o[j]);
      o[j] = mfma_16x16x32(bv1, pa1, o[j]);
    }
    __builtin_amdgcn_s_setprio(0);
    cur ^= 1;
  }

  // epilogue: normalize, transpose O^T -> O via LDS (reuse Kl), coalesced store
  float inv = 1.0f / l_run;
  __syncthreads();                           // all waves done with Kl
  unsigned short* Ol = &Kl[0][0][0];         // view: [4][16][136] (pad vs bank conflicts)
#pragma unroll
  for (int j = 0; j < 8; ++j)
#pragma unroll
    for (int r = 0; r < 4; ++r)
      Ol[w * 2176 + l15 * 136 + j * 16 + lg * 4 + r] = f2bf(o[j][r] * inv);
  asm volatile("s_waitcnt lgkmcnt(0)" ::: "memory");
#pragma unroll
  for (int p = 0; p < 4; ++p) {
    int row = p * 4 + lg;
    bf16x8 vv = *(const bf16x8*)&Ol[w * 2176 + row * 136 + l15 * 8];
    *(bf16x8*)(AO + (size_t)(q0 + w * 16 + row) * 4096 + h * 128 + l15 * 8) = vv;
  }
}

// ---------------- launch ----------------
extern "C" void kernel_launch(void* const* d_in, const int* in_sizes, int n_in,
                              void* d_out, int out_size, void* d_ws, size_t ws_size,
                              hipStream_t stream) {
  const float* x  = (const float*)d_in[0];
  const float* Wq = (const float*)d_in[1];
  const float* Wk = (const float*)d_in[2];
  const float* Wv = (const float*)d_in[3];
  const float* Wo = (const float*)d_in[4];
  const int*   pos = (const int*)d_in[5];
  float* out = (float*)d_out;

  char* p = (char*)d_ws;
  unsigned short* xb  = (unsigned short*)p; p += (size_t)2048 * 4096 * 2;
  unsigned short* wqb = (unsigned short*)p; p += (size_t)4096 * 4096 * 2;
  unsigned short* wkv = (unsigned short*)p; p += (size_t)2048 * 4096 * 2;  // K rows then V rows
  unsigned short* wob = (unsigned short*)p; p += (size_t)4096 * 4096 * 2;
  unsigned short* qb  = (unsigned short*)p; p += (size_t)2048 * 4096 * 2;
  unsigned short* kb  = (unsigned short*)p; p += (size_t)2048 * 1024 * 2;
  unsigned short* vtb = (unsigned short*)p; p += (size_t)1024 * 2048 * 2;
  unsigned short* aob = (unsigned short*)p; p += (size_t)2048 * 4096 * 2;
  float2*         tab = (float2*)p;         p += (size_t)2048 * 64 * 8;

  Conv5 ca;
  ca.x  = (const float4*)x;  ca.wq = (const float4*)Wq; ca.wk = (const float4*)Wk;
  ca.wv = (const float4*)Wv; ca.wo = (const float4*)Wo;
  ca.xb = (ushort4*)xb; ca.wqb = (ushort4*)wqb; ca.wkv = (ushort4*)wkv; ca.wob = (ushort4*)wob;
  k_conv_all<<<4096, 256, 0, stream>>>(ca);
  k_rope_table<<<512, 256, 0, stream>>>(tab);

  k_gemm_bt<0><<<dim3(32, 16), 256, 0, stream>>>(xb, wqb, qb, 2048, 4096, 4096);
  k_gemm_kv<<<dim3(16, 32), 256, 0, stream>>>(xb, wkv, kb, vtb, 2048, 4096);

  const float scale = 0.08838834764831845f;  // 1/sqrt(128), folded into Q
  k_rope_v<32, 5><<<2048, 256, 0, stream>>>(qb, tab, pos, scale);
  k_rope_v<8, 3><<<512, 256, 0, stream>>>(kb, tab, pos, 1.0f);

  k_attn<<<1024, 256, 0, stream>>>(qb, kb, vtb, aob);

  k_gemm_bt<1><<<dim3(32, 16), 256, 0, stream>>>(aob, wob, out, 2048, 4096, 4096);
}

// Round 4
// 479.714 us; speedup vs baseline: 1.7760x; 1.1675x over previous
//
#include <hip/hip_runtime.h>
#include <hip/hip_bf16.h>

#define DEVI __device__ __forceinline__

typedef __attribute__((ext_vector_type(8))) __bf16 bf16x8;
typedef __attribute__((ext_vector_type(4))) float f32x4;

DEVI f32x4 mfma_16x16x32(bf16x8 a, bf16x8 b, f32x4 c) {
  return __builtin_amdgcn_mfma_f32_16x16x32_bf16(a, b, c, 0, 0, 0);
}

// async global->LDS, 16B per lane; LDS dest = wave-uniform base + lane*16
DEVI void gld16(const void* g, void* l) {
  __builtin_amdgcn_global_load_lds(
      reinterpret_cast<const __attribute__((address_space(1))) unsigned int*>(
          reinterpret_cast<unsigned long long>(g)),
      reinterpret_cast<__attribute__((address_space(3))) unsigned int*>(
          reinterpret_cast<unsigned long long>(l)),
      16, 0, 0);
}

DEVI unsigned short f2bf(float f) {
  unsigned u = __builtin_bit_cast(unsigned, f);
  u += 0x7FFFu + ((u >> 16) & 1u);   // RNE
  return (unsigned short)(u >> 16);
}
DEVI float bf2f(unsigned short b) {
  return __builtin_bit_cast(float, (unsigned)b << 16);
}

// ---------------- fused fp32 -> bf16 conversion (all 5 tensors, 1 launch) ----------------
// wqkv layout: rows 0-4095 = Wq, 4096-5119 = Wk, 5120-6143 = Wv  (all [.][4096])
struct Conv5 {
  const float4 *x, *wq, *wk, *wv, *wo;
  ushort4 *xb, *wqkv, *wob;
};
__global__ void k_conv_all(Conv5 a) {
  constexpr int C0 = 2097152;            // x      2048*4096/4
  constexpr int C1 = C0 + 4194304;       // Wq     4096*4096/4
  constexpr int C2 = C1 + 1048576;       // Wk     1024*4096/4
  constexpr int C3 = C2 + 1048576;       // Wv
  constexpr int C4 = C3 + 4194304;       // Wo
  int stride = gridDim.x * blockDim.x;
  for (int i = blockIdx.x * blockDim.x + threadIdx.x; i < C4; i += stride) {
    const float4* src; ushort4* dst; int j;
    if (i < C0)      { src = a.x;  dst = a.xb;             j = i; }
    else if (i < C1) { src = a.wq; dst = a.wqkv;           j = i - C0; }
    else if (i < C2) { src = a.wk; dst = a.wqkv + 4194304; j = i - C1; }
    else if (i < C3) { src = a.wv; dst = a.wqkv + 5242880; j = i - C2; }
    else             { src = a.wo; dst = a.wob;            j = i - C3; }
    float4 v = src[j];
    ushort4 o; o.x = f2bf(v.x); o.y = f2bf(v.y); o.z = f2bf(v.z); o.w = f2bf(v.w);
    dst[j] = o;
  }
}

// ---------------- RoPE table: tab[s*64+d] = (cos, sin) of s * theta^(-d/64) ----------------
__global__ void k_rope_table(float2* __restrict__ tab) {
  int idx = blockIdx.x * blockDim.x + threadIdx.x;   // 2048*64
  int s = idx >> 6, d = idx & 63;
  float invf = powf(10000.0f, -(float)d * (1.0f / 64.0f));
  float f = (float)s * invf;
  tab[idx] = make_float2(cosf(f), sinf(f));
}

// ---------------- RoPE apply, vectorized: 8 (d,d+64) pairs per thread ----------------
template <int NH_, int L2NH>
__global__ void k_rope_v(unsigned short* __restrict__ X, const float2* __restrict__ tab,
                         const int* __restrict__ pos, float scale) {
  int t = blockIdx.x * blockDim.x + threadIdx.x;     // 2048*NH_*8 threads
  int d0 = (t & 7) * 8;
  int sh = t >> 3;
  int s  = sh >> L2NH;
  int h  = sh & (NH_ - 1);
  size_t base = (size_t)s * (NH_ * 128) + h * 128 + d0;
  const float4* tf = (const float4*)(tab + (size_t)pos[s] * 64 + d0);
  unsigned short a[8], b[8], oa[8], ob[8];
  *(ushort4*)&a[0] = *(const ushort4*)(X + base);
  *(ushort4*)&a[4] = *(const ushort4*)(X + base + 4);
  *(ushort4*)&b[0] = *(const ushort4*)(X + base + 64);
  *(ushort4*)&b[4] = *(const ushort4*)(X + base + 68);
#pragma unroll
  for (int j = 0; j < 4; ++j) {
    float4 cs = tf[j];                               // c(2j), s(2j), c(2j+1), s(2j+1)
    float x1 = bf2f(a[2*j]),   x2 = bf2f(b[2*j]);
    float y1 = bf2f(a[2*j+1]), y2 = bf2f(b[2*j+1]);
    oa[2*j]   = f2bf((x1 * cs.x - x2 * cs.y) * scale);
    ob[2*j]   = f2bf((x2 * cs.x + x1 * cs.y) * scale);
    oa[2*j+1] = f2bf((y1 * cs.z - y2 * cs.w) * scale);
    ob[2*j+1] = f2bf((y2 * cs.z + y1 * cs.w) * scale);
  }
  *(ushort4*)(X + base)      = *(ushort4*)&oa[0];
  *(ushort4*)(X + base + 4)  = *(ushort4*)&oa[4];
  *(ushort4*)(X + base + 64) = *(ushort4*)&ob[0];
  *(ushort4*)(X + base + 68) = *(ushort4*)&ob[4];
}

// ---------------- GEMM: C = A(Mx4096) * B(Nx4096)^T, BK=64, XOR-swizzled LDS ----------------
// swizzle invariant: row r, 16B-slot c holds k-chunk c ^ (r&7).
// EPI 0: split QKV epilogue (col<4096 -> Q bf16; <5120 -> K bf16; else Vt transposed bf16)
// EPI 1: f32 C[row*4096+col]
template <int EPI>
__global__ __launch_bounds__(256, 2)
void k_gemm64(const unsigned short* __restrict__ A,
              const unsigned short* __restrict__ B,
              void* __restrict__ Cp,
              unsigned short* __restrict__ Kp,
              unsigned short* __restrict__ Vtp,
              int K) {
  __shared__ __align__(16) unsigned short As[128][64];   // 16 KB
  __shared__ __align__(16) unsigned short Bs[128][64];   // 16 KB
  const int tid  = threadIdx.x;
  const int lane = tid & 63;
  const int wave = tid >> 6;
  const int bm = blockIdx.y * 128;
  const int bn = blockIdx.x * 128;
  const int wm = (wave >> 1) * 64;
  const int wn = (wave & 1) * 64;
  const int l15 = lane & 15;
  const int lg  = lane >> 4;

  f32x4 acc[4][4] = {};

  // staging: wave w owns rows [w*32, w*32+32), 4 chunks of 8 rows (128B/row).
  // lane -> local row = lane>>3, 16B-slot = lane&7; global col pre-swizzled.
  const int srow  = lane >> 3;                 // 0..7 (== row&7)
  const int scol  = ((lane & 7) ^ srow) * 8;   // element offset within row
  const unsigned short* aS = A + (size_t)(bm + wave * 32 + srow) * K + scol;
  const unsigned short* bS = B + (size_t)(bn + wave * 32 + srow) * K + scol;

  for (int k0 = 0; k0 < K; k0 += 64) {
    __syncthreads();
#pragma unroll
    for (int c = 0; c < 4; ++c) {
      gld16(aS + (size_t)(c * 8) * K + k0, &As[wave * 32 + c * 8][0]);
      gld16(bS + (size_t)(c * 8) * K + k0, &Bs[wave * 32 + c * 8][0]);
    }
    __syncthreads();

#pragma unroll
    for (int ks = 0; ks < 2; ++ks) {
      bf16x8 a[4], b[4];
#pragma unroll
      for (int m = 0; m < 4; ++m)
        a[m] = *(const bf16x8*)&As[wm + m * 16 + l15][((ks * 4 + lg) ^ (l15 & 7)) * 8];
#pragma unroll
      for (int n = 0; n < 4; ++n)
        b[n] = *(const bf16x8*)&Bs[wn + n * 16 + l15][((ks * 4 + lg) ^ (l15 & 7)) * 8];
#pragma unroll
      for (int m = 0; m < 4; ++m)
#pragma unroll
        for (int n = 0; n < 4; ++n)
          acc[m][n] = mfma_16x16x32(a[m], b[n], acc[m][n]);
    }
  }

#pragma unroll
  for (int m = 0; m < 4; ++m)
#pragma unroll
    for (int n = 0; n < 4; ++n)
#pragma unroll
      for (int r = 0; r < 4; ++r) {
        int row = bm + wm + m * 16 + lg * 4 + r;
        int col = bn + wn + n * 16 + l15;
        float v = acc[m][n][r];
        if (EPI == 0) {
          if (col < 4096)      ((unsigned short*)Cp)[(size_t)row * 4096 + col] = f2bf(v);
          else if (col < 5120) Kp[(size_t)row * 1024 + (col - 4096)] = f2bf(v);
          else                 Vtp[(size_t)(col - 5120) * 2048 + row] = f2bf(v);
        } else {
          ((float*)Cp)[(size_t)row * 4096 + col] = v;
        }
      }
}

// ---------------- Flash attention v4: swapped QK^T, per-lane softmax, defer-rescale ----------------
// causal, GQA 32Q/8KV, HD=128, KVBLK=64, double-buffered, XOR-swizzled LDS.
// S^T = mfma(K,Q): lane (lg,l15) holds S^T[kv0+n*16+lg*4+r][q=l15] -> softmax per-lane.
// O^T = mfma(Vt,P): lane holds O^T[d=j*16+lg*4+r][q=l15]; transposed out via LDS.
__global__ __launch_bounds__(256, 2)
void k_attn(const unsigned short* __restrict__ Q,    // [2048][4096], pre-scaled
            const unsigned short* __restrict__ Kb,   // [2048][1024]
            const unsigned short* __restrict__ Vt,   // [1024][2048]  (d-major)
            unsigned short* __restrict__ AO) {       // [2048][4096]
  __shared__ __align__(16) unsigned short Kl[2][64][128];  // 32 KB (reused as Ol[4][16][136])
  __shared__ __align__(16) unsigned short Vl[2][128][64];  // 32 KB
  __shared__ __align__(16) unsigned short Pl[4][16][72];   // 9 KB
  const int tid = threadIdx.x, lane = tid & 63, w = tid >> 6;
  const int bid = blockIdx.x;
  const int qi = 31 - (bid >> 5);            // heavy blocks dispatched first
  const int h  = bid & 31;
  const int q0 = qi * 64;
  const int kh = h >> 2;
  const int l15 = lane & 15, lg = lane >> 4;

  bf16x8 qf[4];
  {
    const unsigned short* qr = Q + (size_t)(q0 + w * 16 + l15) * 4096 + h * 128;
#pragma unroll
    for (int ks = 0; ks < 4; ++ks) qf[ks] = *(const bf16x8*)(qr + ks * 32 + lg * 8);
  }

  f32x4 o[8] = {};
  float m_run = -1e30f, l_run = 0.f;
  const int nkb = qi + 1;
  const int myq = q0 + w * 16 + l15;         // this lane's q row

  auto stageK = [&](int buf, int kv0) {
#pragma unroll
    for (int c = 0; c < 4; ++c) {
      int row = 16 * w + 4 * c + lg;
      gld16(Kb + (size_t)(kv0 + row) * 1024 + kh * 128 + ((l15 ^ (row & 7)) * 8),
            &Kl[buf][16 * w + 4 * c][0]);
    }
  };
  auto stageV = [&](int buf, int kv0) {
#pragma unroll
    for (int c = 0; c < 4; ++c) {
      int row = 32 * w + 8 * c + (lane >> 3);
      gld16(Vt + (size_t)(kh * 128 + row) * 2048 + kv0 + (((lane & 7) ^ (row & 7)) * 8),
            &Vl[buf][32 * w + 8 * c][0]);
    }
  };

  stageK(0, 0);
  stageV(0, 0);
  int cur = 0;

  for (int kb = 0; kb < nkb; ++kb) {
    const int kv0 = kb * 64;
    __syncthreads();                         // buf[cur] staged; buf[cur^1] free
    if (kb + 1 < nkb) { stageK(cur ^ 1, kv0 + 64); stageV(cur ^ 1, kv0 + 64); }

    // S^T = K Q^T  (64 kv-rows x 16 q-cols); q is lane-local (= l15)
    f32x4 s[4] = {};
    __builtin_amdgcn_s_setprio(1);
#pragma unroll
    for (int ks = 0; ks < 4; ++ks)
#pragma unroll
      for (int n = 0; n < 4; ++n) {
        bf16x8 bk = *(const bf16x8*)&Kl[cur][n * 16 + l15][((ks * 4 + lg) ^ (l15 & 7)) * 8];
        s[n] = mfma_16x16x32(bk, qf[ks], s[n]);
      }
    __builtin_amdgcn_s_setprio(0);

    if (kb == nkb - 1) {                     // causal mask: diagonal tile only
#pragma unroll
      for (int n = 0; n < 4; ++n)
#pragma unroll
        for (int r = 0; r < 4; ++r)
          if (kv0 + n * 16 + lg * 4 + r > myq) s[n][r] = -1e30f;
    }

    // per-lane max over this lane's 16 scores; reduce across lg (xor 16,32)
    float mx = -1e30f;
#pragma unroll
    for (int n = 0; n < 4; ++n)
      mx = fmaxf(mx, fmaxf(fmaxf(s[n][0], s[n][1]), fmaxf(s[n][2], s[n][3])));
    mx = fmaxf(mx, __shfl_xor(mx, 16));
    mx = fmaxf(mx, __shfl_xor(mx, 32));

    // T13 defer-rescale: skip o-rescale while max growth <= 8 (P bounded by e^8)
    if (!__all(mx <= m_run + 8.0f)) {
      float mn = fmaxf(m_run, mx);
      float fac = __expf(m_run - mn);
      m_run = mn;
      l_run *= fac;
#pragma unroll
      for (int j = 0; j < 8; ++j) {
        o[j][0] *= fac; o[j][1] *= fac; o[j][2] *= fac; o[j][3] *= fac;
      }
    }
    float rs = 0.f;
#pragma unroll
    for (int n = 0; n < 4; ++n)
#pragma unroll
      for (int r = 0; r < 4; ++r) {
        float pv = __expf(s[n][r] - m_run);
        s[n][r] = pv;
        rs += pv;
      }
    rs += __shfl_xor(rs, 16);
    rs += __shfl_xor(rs, 32);
    l_run += rs;

    // P[q=l15][kv] -> per-wave LDS (4x ds_write_b64) -> B-layout fragments
#pragma unroll
    for (int n = 0; n < 4; ++n) {
      ushort4 pk;
      pk.x = f2bf(s[n][0]); pk.y = f2bf(s[n][1]); pk.z = f2bf(s[n][2]); pk.w = f2bf(s[n][3]);
      *(ushort4*)&Pl[w][l15][n * 16 + lg * 4] = pk;
    }
    asm volatile("s_waitcnt lgkmcnt(0)" ::: "memory");
    bf16x8 pa0 = *(const bf16x8*)&Pl[w][l15][lg * 8];
    bf16x8 pa1 = *(const bf16x8*)&Pl[w][l15][32 + lg * 8];

    // O^T += V^T P^T  (A = Vt rows d, B = P rows q)
    __builtin_amdgcn_s_setprio(1);
#pragma unroll
    for (int j = 0; j < 8; ++j) {
      bf16x8 bv0 = *(const bf16x8*)&Vl[cur][j * 16 + l15][(lg ^ (l15 & 7)) * 8];
      bf16x8 bv1 = *(const bf16x8*)&Vl[cur][j * 16 + l15][((4 + lg) ^ (l15 & 7)) * 8];
      o[j] = mfma_16x16x32(bv0, pa0, o[j]);
      o[j] = mfma_16x16x32(bv1, pa1, o[j]);
    }
    __builtin_amdgcn_s_setprio(0);
    cur ^= 1;
  }

  // epilogue: normalize, transpose O^T -> O via LDS (reuse Kl), coalesced store
  float inv = 1.0f / l_run;
  __syncthreads();                           // all waves done with Kl
  unsigned short* Ol = &Kl[0][0][0];         // view: [4][16][136]
#pragma unroll
  for (int j = 0; j < 8; ++j)
#pragma unroll
    for (int r = 0; r < 4; ++r)
      Ol[w * 2176 + l15 * 136 + j * 16 + lg * 4 + r] = f2bf(o[j][r] * inv);
  asm volatile("s_waitcnt lgkmcnt(0)" ::: "memory");
#pragma unroll
  for (int p = 0; p < 4; ++p) {
    int row = p * 4 + lg;
    bf16x8 vv = *(const bf16x8*)&Ol[w * 2176 + row * 136 + l15 * 8];
    *(bf16x8*)(AO + (size_t)(q0 + w * 16 + row) * 4096 + h * 128 + l15 * 8) = vv;
  }
}

// ---------------- launch ----------------
extern "C" void kernel_launch(void* const* d_in, const int* in_sizes, int n_in,
                              void* d_out, int out_size, void* d_ws, size_t ws_size,
                              hipStream_t stream) {
  const float* x  = (const float*)d_in[0];
  const float* Wq = (const float*)d_in[1];
  const float* Wk = (const float*)d_in[2];
  const float* Wv = (const float*)d_in[3];
  const float* Wo = (const float*)d_in[4];
  const int*   pos = (const int*)d_in[5];
  float* out = (float*)d_out;

  char* p = (char*)d_ws;
  unsigned short* xb   = (unsigned short*)p; p += (size_t)2048 * 4096 * 2;
  unsigned short* wqkv = (unsigned short*)p; p += (size_t)6144 * 4096 * 2;  // Wq,Wk,Wv rows
  unsigned short* wob  = (unsigned short*)p; p += (size_t)4096 * 4096 * 2;
  unsigned short* qb   = (unsigned short*)p; p += (size_t)2048 * 4096 * 2;
  unsigned short* kb   = (unsigned short*)p; p += (size_t)2048 * 1024 * 2;
  unsigned short* vtb  = (unsigned short*)p; p += (size_t)1024 * 2048 * 2;
  unsigned short* aob  = (unsigned short*)p; p += (size_t)2048 * 4096 * 2;
  float2*         tab  = (float2*)p;         p += (size_t)2048 * 64 * 8;

  Conv5 ca;
  ca.x  = (const float4*)x;  ca.wq = (const float4*)Wq; ca.wk = (const float4*)Wk;
  ca.wv = (const float4*)Wv; ca.wo = (const float4*)Wo;
  ca.xb = (ushort4*)xb; ca.wqkv = (ushort4*)wqkv; ca.wob = (ushort4*)wob;
  k_conv_all<<<4096, 256, 0, stream>>>(ca);
  k_rope_table<<<512, 256, 0, stream>>>(tab);

  // merged QKV projection: C[2048][6144] split into qb / kb / vtb^T
  k_gemm64<0><<<dim3(48, 16), 256, 0, stream>>>(xb, wqkv, qb, kb, vtb, 4096);

  const float scale = 0.08838834764831845f;  // 1/sqrt(128), folded into Q
  k_rope_v<32, 5><<<2048, 256, 0, stream>>>(qb, tab, pos, scale);
  k_rope_v<8, 3><<<512, 256, 0, stream>>>(kb, tab, pos, 1.0f);

  k_attn<<<1024, 256, 0, stream>>>(qb, kb, vtb, aob);

  k_gemm64<1><<<dim3(32, 16), 256, 0, stream>>>(aob, wob, out, nullptr, nullptr, 4096);
}